// Round 14
// baseline (181.402 us; speedup 1.0000x reference)
//
#include <hip/hip_runtime.h>

typedef __bf16 bf16x8 __attribute__((ext_vector_type(8)));
typedef float floatx4 __attribute__((ext_vector_type(4)));

#define EPSF 1e-6f

__device__ inline unsigned short f2bf(float f) {  // RNE
  union { float f; unsigned u; } x; x.f = f;
  unsigned r = x.u + 0x7FFFu + ((x.u >> 16) & 1u);
  return (unsigned short)(r >> 16);
}
__device__ inline float bf2f(unsigned short u) {
  union { unsigned u; float f; } x; x.u = ((unsigned)u) << 16;
  return x.f;
}
// pack two f32 -> bf16x2 dword, round-half-up
__device__ inline unsigned pk2bf(float lo, float hi) {
  union { float f; unsigned u; } a, b; a.f = lo; b.f = hi;
  unsigned ua = a.u + 0x8000u, ub = b.u + 0x8000u;
  return (ub & 0xFFFF0000u) | (ua >> 16);
}
// single-instruction v_exp_f32 (input in log2 domain — scale folded into Q weights)
__device__ inline float fexp2(float x) { return __builtin_amdgcn_exp2f(x); }

__device__ inline floatx4 mfma16(bf16x8 a, bf16x8 b, floatx4 c) {
  return __builtin_amdgcn_mfma_f32_16x16x32_bf16(a, b, c, 0, 0, 0);
}

__device__ inline void gll16(const unsigned short* g, unsigned short* l) {
  __builtin_amdgcn_global_load_lds((__attribute__((address_space(1))) void*)g,
                                   (__attribute__((address_space(3))) void*)l, 16, 0, 0);
}

// ctx permutation sigma^-1 (PV k-dim): stored pos p in a 32-chunk holds original ctx c
__device__ __host__ inline int sigma_inv(int p) {
  const int qq = p >> 3, jj = p & 7;
  return (jj < 4) ? (qq * 4 + jj) : (16 + qq * 4 + jj - 4);
}

// ---------- merged prep: x cast | qkv_w cast (Q-scaled) | proj_w cast with k-dim gather-perm | policy pack ----------
// feature perm pi(c) = 4*(c%16) + c/16 within each 64-block (qkv GEMM packed epilogue)
__global__ __launch_bounds__(256) void prep_kernel(const float* __restrict__ x,
                                                   const float* __restrict__ qkv_w,
                                                   const float* __restrict__ proj_w,
                                                   const float* __restrict__ policy,
                                                   unsigned short* __restrict__ xb,
                                                   unsigned short* __restrict__ wqkv,
                                                   unsigned short* __restrict__ wproj,
                                                   unsigned short* __restrict__ pbf) {
  const int bid = blockIdx.x, tid = threadIdx.x;
  if (bid < 3072) {  // x cast: 6291456 elems
    const int i = bid * 2048 + tid * 8;
    float4 v0 = *(const float4*)(x + i);
    float4 v1 = *(const float4*)(x + i + 4);
    __align__(16) unsigned short o[8] = {f2bf(v0.x), f2bf(v0.y), f2bf(v0.z), f2bf(v0.w),
                                         f2bf(v1.x), f2bf(v1.y), f2bf(v1.z), f2bf(v1.w)};
    *(float4*)(xb + i) = *(float4*)o;
  } else if (bid < 3936) {  // qkv_w cast: 1769472 elems, first 589824 (Q rows) * 0.125*log2(e)
    const int i = (bid - 3072) * 2048 + tid * 8;
    const float s = (i < 589824) ? 0.18033688011112042f : 1.0f;
    float4 v0 = *(const float4*)(qkv_w + i);
    float4 v1 = *(const float4*)(qkv_w + i + 4);
    __align__(16) unsigned short o[8] = {
        f2bf(v0.x * s), f2bf(v0.y * s), f2bf(v0.z * s), f2bf(v0.w * s),
        f2bf(v1.x * s), f2bf(v1.y * s), f2bf(v1.z * s), f2bf(v1.w * s)};
    *(float4*)(wqkv + i) = *(float4*)o;
  } else if (bid < 4224) {  // proj_w cast with in-dim pi perm: 589824 elems
    const int i0 = (bid - 3936) * 2048 + tid * 8;  // dest index (row-contig)
    const int base = (i0 / 768) * 768 + ((i0 % 768) & ~63);
    __align__(16) unsigned short o[8];
#pragma unroll
    for (int t = 0; t < 8; t++) {
      const int cp = (i0 + t) & 63;                 // stored position within 64-block
      const int c = 16 * (cp & 3) + (cp >> 2);      // original column
      o[t] = f2bf(proj_w[base + c]);
    }
    *(float4*)(wproj + i0) = *(float4*)o;
  } else {  // policy pack: 8192 elems, ctx-perm sigma per 32-chunk
    const int idx = (bid - 4224) * 256 + tid;
    const int b = idx >> 10, g = idx & 1023;
    const int c = ((g >> 5) << 5) + sigma_inv(g & 31);
    pbf[idx] = f2bf(policy[b * 1024 + c]);
  }
}

// ---------- bf16 GEMM: BK=64, XOR-8 swizzle, XCD y-band grid swizzle for L2 locality ----------
// 1D grid; y = (bid&7)*8 + ((bid>>3)&7), x = bid>>6 — XCD k touches one 1024-row A band.
// EP=0 (BN=128): bf16 out with 64-block col-perm pi (packed dwordx2 stores).
// EP=1 (BN=64): f32 out + bias, natural layout.  W = min waves/EU.
template <int EP, int BN, int W>
__global__ __launch_bounds__(256, W) void gemm_bt(const unsigned short* __restrict__ A,
                                                  const unsigned short* __restrict__ Bt,
                                                  void* __restrict__ Cout,
                                                  const float* __restrict__ bias,
                                                  int M, int N, int K) {
  constexpr int J = BN / 32;
  __shared__ __align__(16) unsigned short sA[128 * 64];
  __shared__ __align__(16) unsigned short sB[BN * 64];
  const int bid = blockIdx.x;
  const int yb = (bid & 7) * 8 + ((bid >> 3) & 7);
  const int xb_ = bid >> 6;
  const int m0 = yb * 128, n0 = xb_ * BN;
  const int tid = threadIdx.x;
  const int lane = tid & 63, wave = tid >> 6;
  const int qd = lane >> 4, l15 = lane & 15;
  const int wr = (wave >> 1) * 64, wc = (wave & 1) * (BN / 2);
  const int srow = tid >> 3;
  const int scb = (tid & 7) ^ (srow & 7);
  const unsigned short* Ag = A + (long)(m0 + srow) * K + scb * 8;
  const unsigned short* Bg = Bt + (long)(n0 + srow) * K + scb * 8;
  const int x7 = l15 & 7;
  floatx4 acc[4][J] = {};
  for (int k0 = 0; k0 < K; k0 += 64) {
    __syncthreads();
#pragma unroll
    for (int p = 0; p < 4; p++) gll16(Ag + (long)(p * 32) * K + k0, sA + p * 2048 + wave * 512);
#pragma unroll
    for (int p = 0; p < J; p++) gll16(Bg + (long)(p * 32) * K + k0, sB + p * 2048 + wave * 512);
    __syncthreads();
#pragma unroll
    for (int s = 0; s < 2; s++) {
      const int cw = ((s * 4 + qd) ^ x7) * 8;
      bf16x8 af[4], bf[J];
#pragma unroll
      for (int i = 0; i < 4; i++) af[i] = *(const bf16x8*)&sA[(wr + i * 16 + l15) * 64 + cw];
#pragma unroll
      for (int j = 0; j < J; j++) bf[j] = *(const bf16x8*)&sB[(wc + j * 16 + l15) * 64 + cw];
#pragma unroll
      for (int i = 0; i < 4; i++)
#pragma unroll
        for (int j = 0; j < J; j++) acc[i][j] = mfma16(af[i], bf[j], acc[i][j]);
    }
  }
  if constexpr (EP == 0) {
    // feature f = wc + 16j + l15 stored at col' = wc + 4*l15 + j  (pi within 64-block)
#pragma unroll
    for (int i = 0; i < 4; i++)
#pragma unroll
      for (int r = 0; r < 4; r++) {
        const int row = m0 + wr + i * 16 + qd * 4 + r;
        __align__(8) unsigned short pk[4];
#pragma unroll
        for (int j = 0; j < 4; j++) pk[j] = f2bf(acc[i][j][r]);
        *(uint2*)((unsigned short*)Cout + (long)row * N + n0 + wc + 4 * l15) = *(uint2*)pk;
      }
  } else {
#pragma unroll
    for (int i = 0; i < 4; i++)
#pragma unroll
      for (int j = 0; j < J; j++) {
        const int col = n0 + wc + j * 16 + l15;
#pragma unroll
        for (int r = 0; r < 4; r++) {
          const int row = m0 + wr + i * 16 + qd * 4 + r;
          ((float*)Cout)[(long)row * N + col] = acc[i][j][r] + bias[col];
        }
      }
  }
}

// ---------- V transpose + policy fold + ctx sigma-perm ----------
__global__ __launch_bounds__(256) void transpose_v(const unsigned short* __restrict__ qkv,
                                                   const float* __restrict__ policy,
                                                   unsigned short* __restrict__ vTp) {
  __shared__ unsigned short tile[64][72];
  __shared__ float sPol[64];
  const int bh = blockIdx.y;
  const int b = bh / 12, h = bh % 12;
  const int n0 = blockIdx.x * 64;
  const int t = threadIdx.x;
  if (t < 64) sPol[t] = policy[b * 1024 + n0 + t];
  {
    const int nr = t >> 2, dc = (t & 3) * 16;
    const unsigned short* src = qkv + (long)(b * 1024 + n0 + nr) * 2304 + 2 * 768 + h * 64 + dc;
    float4 v0 = *(const float4*)src;
    float4 v1 = *(const float4*)(src + 8);
    *(float4*)&tile[nr][dc] = v0;
    *(float4*)&tile[nr][dc + 8] = v1;
  }
  __syncthreads();
  {
    const int d = t >> 2, nc = (t & 3) * 16;
    __align__(16) unsigned short o[16];
#pragma unroll
    for (int jj = 0; jj < 16; jj++) {
      const int cc = nc + jj;
      const int cl = (cc & 32) + sigma_inv(cc & 31);
      o[jj] = f2bf(bf2f(tile[cl][d]) * sPol[cl]);
    }
    unsigned short* dst = vTp + (long)(bh * 64 + d) * 1024 + n0 + nc;
    *(float4*)dst = *(float4*)&o[0];
    *(float4*)(dst + 8) = *(float4*)&o[8];
  }
}

// ---------- attention v10: software-pipelined — QK(i+1) overlaps exp/PV(i) (MFMA+VALU co-issue) ----------
// K ring = 2 slots (K(j) staged iter j-2, read iter j-1), V ring = 3 slots (V(j) staged iter j-2, read iter j).
__global__ __launch_bounds__(256, 3) void attn_kernel(const unsigned short* __restrict__ qkv,
                                                      const unsigned short* __restrict__ vTp,
                                                      const unsigned short* __restrict__ pbf,
                                                      const float* __restrict__ policy,
                                                      unsigned short* __restrict__ aout) {
  __shared__ __align__(16) unsigned short sK[2][2048];  // 32 ctx x 64 d, slot cb = c ^ (row&7)
  __shared__ __align__(16) unsigned short sV[3][2048];  // 64 d x 32 ctx, slot cb = c ^ ((d^(d>>2))&3)
  __shared__ __align__(16) unsigned short sPv[1024];
  __shared__ float sD[4][32];
  const int bid = blockIdx.x;
  const int bh = bid % 96, qt = bid / 96;  // bh-fast for XCD L2 locality
  const int b = bh / 12, h = bh % 12;
  const int tid = threadIdx.x;
  const int wave = tid >> 6, lane = tid & 63;
  const int qd = lane >> 4, l15 = lane & 15;
  const int q0 = qt * 128 + wave * 32;
  const unsigned short* qb = qkv + (long)(b * 1024 + q0 + l15) * 2304 + h * 64 + qd * 8;
  bf16x8 qf00 = *(const bf16x8*)qb;  // Q pre-scaled by 0.125*log2e
  bf16x8 qf01 = *(const bf16x8*)(qb + 32);
  bf16x8 qf10 = *(const bf16x8*)(qb + (long)16 * 2304);
  bf16x8 qf11 = *(const bf16x8*)(qb + (long)16 * 2304 + 32);
  if (tid < 128) *(float4*)(sPv + tid * 8) = *(const float4*)(pbf + b * 1024 + tid * 8);
  const int krow = wave * 8 + (lane >> 3);
  const int kcb = (lane & 7) ^ (lane >> 3);
  const unsigned short* kgl = qkv + (long)(b * 1024 + krow) * 2304 + 768 + h * 64 + kcb * 8;
  const int vrow = tid >> 2;
  const int vcb = (tid & 3) ^ ((vrow ^ (vrow >> 2)) & 3);
  const unsigned short* vgl = vTp + (long)(bh * 64 + vrow) * 1024 + vcb * 8;
  const int x7 = l15 & 7;
  const int vsw = (qd ^ ((l15 ^ (l15 >> 2)) & 3)) * 8;
  floatx4 O0[4] = {}, O1[4] = {};
  floatx4 Dl0 = {}, Dl1 = {};
  const floatx4 z = {0.f, 0.f, 0.f, 0.f};
  // prologue: stage chunks 0 (slot 0) and 1 (slot 1), publish, compute QK(0)
  gll16(kgl, &sK[0][wave * 512]);
  gll16(vgl, &sV[0][wave * 512]);
  gll16(kgl + (long)32 * 2304, &sK[1][wave * 512]);
  gll16(vgl + 32, &sV[1][wave * 512]);
  __builtin_amdgcn_s_waitcnt(0);
  __syncthreads();
  floatx4 tA0, tB0, tA1, tB1;
  {
    bf16x8 k00 = *(const bf16x8*)&sK[0][(0 * 16 + l15) * 64 + ((0 + qd) ^ x7) * 8];
    bf16x8 k01 = *(const bf16x8*)&sK[0][(0 * 16 + l15) * 64 + ((4 + qd) ^ x7) * 8];
    bf16x8 k10 = *(const bf16x8*)&sK[0][(1 * 16 + l15) * 64 + ((0 + qd) ^ x7) * 8];
    bf16x8 k11 = *(const bf16x8*)&sK[0][(1 * 16 + l15) * 64 + ((4 + qd) ^ x7) * 8];
    tA0 = mfma16(k01, qf01, mfma16(k00, qf00, z));
    tB0 = mfma16(k11, qf01, mfma16(k10, qf00, z));
    tA1 = mfma16(k01, qf11, mfma16(k00, qf10, z));
    tB1 = mfma16(k11, qf11, mfma16(k10, qf10, z));
  }
  for (int it = 0; it < 32; ++it) {
    if (it + 2 < 32) {  // stage chunk it+2: K slot (it+2)&1 == it&1 (freed after QK(it) last iter), V slot (it+2)%3
      const long cn = 32 * (it + 2);
      gll16(kgl + cn * 2304, &sK[it & 1][wave * 512]);
      gll16(vgl + cn, &sV[(it + 2) % 3][wave * 512]);
    }
    // exp(it): consumes t-registers (s-values of chunk it)
    uint4 pu0, pu1;
    pu0.x = pk2bf(fexp2(tA0[0]), fexp2(tA0[1]));
    pu0.y = pk2bf(fexp2(tA0[2]), fexp2(tA0[3]));
    pu0.z = pk2bf(fexp2(tB0[0]), fexp2(tB0[1]));
    pu0.w = pk2bf(fexp2(tB0[2]), fexp2(tB0[3]));
    pu1.x = pk2bf(fexp2(tA1[0]), fexp2(tA1[1]));
    pu1.y = pk2bf(fexp2(tA1[2]), fexp2(tA1[3]));
    pu1.z = pk2bf(fexp2(tB1[0]), fexp2(tB1[1]));
    pu1.w = pk2bf(fexp2(tB1[2]), fexp2(tB1[3]));
    bf16x8 pf0 = *(bf16x8*)&pu0;
    bf16x8 pf1 = *(bf16x8*)&pu1;
    // QK(it+1): overlaps exp/PV on the matrix pipe (K staged 2 iters ago, published last barrier)
    if (it + 1 < 32) {
      const unsigned short* kb = &sK[(it + 1) & 1][0];
      bf16x8 k00 = *(const bf16x8*)&kb[(0 * 16 + l15) * 64 + ((0 + qd) ^ x7) * 8];
      bf16x8 k01 = *(const bf16x8*)&kb[(0 * 16 + l15) * 64 + ((4 + qd) ^ x7) * 8];
      bf16x8 k10 = *(const bf16x8*)&kb[(1 * 16 + l15) * 64 + ((0 + qd) ^ x7) * 8];
      bf16x8 k11 = *(const bf16x8*)&kb[(1 * 16 + l15) * 64 + ((4 + qd) ^ x7) * 8];
      tA0 = mfma16(k01, qf01, mfma16(k00, qf00, z));
      tB0 = mfma16(k11, qf01, mfma16(k10, qf00, z));
      tA1 = mfma16(k01, qf11, mfma16(k00, qf10, z));
      tB1 = mfma16(k11, qf11, mfma16(k10, qf10, z));
    }
    // PV(it) + denominator
    const unsigned short* vb = &sV[it % 3][0];
    bf16x8 pv = *(const bf16x8*)&sPv[it * 32 + qd * 8];
    bf16x8 vf0 = *(const bf16x8*)&vb[(0 * 16 + l15) * 32 + vsw];
    bf16x8 vf1 = *(const bf16x8*)&vb[(1 * 16 + l15) * 32 + vsw];
    bf16x8 vf2 = *(const bf16x8*)&vb[(2 * 16 + l15) * 32 + vsw];
    bf16x8 vf3 = *(const bf16x8*)&vb[(3 * 16 + l15) * 32 + vsw];
    Dl0 = mfma16(pf0, pv, Dl0);
    Dl1 = mfma16(pf1, pv, Dl1);
    O0[0] = mfma16(pf0, vf0, O0[0]); O1[0] = mfma16(pf1, vf0, O1[0]);
    O0[1] = mfma16(pf0, vf1, O0[1]); O1[1] = mfma16(pf1, vf1, O1[1]);
    O0[2] = mfma16(pf0, vf2, O0[2]); O1[2] = mfma16(pf1, vf2, O1[2]);
    O0[3] = mfma16(pf0, vf3, O0[3]); O1[3] = mfma16(pf1, vf3, O1[3]);
    __builtin_amdgcn_s_waitcnt(0);  // drain own prefetch DMA (cross-wave publish) before barrier
    __syncthreads();
  }
  // ---- diagonal correction: O[q] += e_qq(1-p_q) V[q]; l_q += e_qq(1-p_q) ----
  {
    const unsigned short* kd = qkv + (long)(b * 1024 + q0 + l15) * 2304 + 768 + h * 64 + qd * 8;
    bf16x8 kd00 = *(const bf16x8*)kd;
    bf16x8 kd01 = *(const bf16x8*)(kd + 32);
    bf16x8 kd10 = *(const bf16x8*)(kd + (long)16 * 2304);
    bf16x8 kd11 = *(const bf16x8*)(kd + (long)16 * 2304 + 32);
    float part0 = 0.f, part1 = 0.f;
#pragma unroll
    for (int jj = 0; jj < 8; jj++) {
      part0 += (float)qf00[jj] * (float)kd00[jj] + (float)qf01[jj] * (float)kd01[jj];
      part1 += (float)qf10[jj] * (float)kd10[jj] + (float)qf11[jj] * (float)kd11[jj];
    }
    part0 += __shfl_xor(part0, 16); part0 += __shfl_xor(part0, 32);
    part1 += __shfl_xor(part1, 16); part1 += __shfl_xor(part1, 32);
    const float p0 = policy[b * 1024 + q0 + l15];
    const float p1 = policy[b * 1024 + q0 + 16 + l15];
    if (qd == 0) {
      sD[wave][l15] = fexp2(part0) * (1.0f - p0);
      sD[wave][16 + l15] = fexp2(part1) * (1.0f - p1);
    }
    __builtin_amdgcn_s_waitcnt(0);
    const unsigned short* vdiag = qkv + (long)(b * 1024 + q0) * 2304 + 1536 + h * 64 + l15;
#pragma unroll
    for (int r = 0; r < 4; r++) {
      const int row = qd * 4 + r;
      const float c0v = sD[wave][row], c1v = sD[wave][16 + row];
#pragma unroll
      for (int j = 0; j < 4; j++) {
        O0[j][r] += c0v * bf2f(vdiag[(long)row * 2304 + j * 16]);
        O1[j][r] += c1v * bf2f(vdiag[(long)(16 + row) * 2304 + j * 16]);
      }
      Dl0[r] += c0v;
      Dl1[r] += c1v;
    }
  }
  const long ob = (long)(b * 1024 + q0 + qd * 4) * 768 + h * 64 + l15;
#pragma unroll
  for (int r = 0; r < 4; r++) {
    const float li0 = 1.0f / (Dl0[r] + EPSF);
    const float li1 = 1.0f / (Dl1[r] + EPSF);
#pragma unroll
    for (int j = 0; j < 4; j++) {
      aout[ob + (long)r * 768 + j * 16] = f2bf(O0[j][r] * li0);
      aout[ob + (long)(16 * 768) + r * 768 + j * 16] = f2bf(O1[j][r] * li1);
    }
  }
}

extern "C" void kernel_launch(void* const* d_in, const int* in_sizes, int n_in,
                              void* d_out, int out_size, void* d_ws, size_t ws_size,
                              hipStream_t stream) {
  const float* x      = (const float*)d_in[0];   // [8,1024,768]
  const float* policy = (const float*)d_in[1];   // [8,1024,1]
  const float* qkv_w  = (const float*)d_in[2];   // [2304,768]
  const float* proj_w = (const float*)d_in[3];   // [768,768]
  const float* proj_b = (const float*)d_in[4];   // [768]
  float* out = (float*)d_out;                    // [8,1024,768] fp32

  char* ws = (char*)d_ws;
  unsigned short* xb    = (unsigned short*)(ws + 0);         // 12,582,912 B
  unsigned short* wqkv  = (unsigned short*)(ws + 12582912);  //  3,538,944 B
  unsigned short* wproj = (unsigned short*)(ws + 16121856);  //  1,179,648 B
  unsigned short* qkvb  = (unsigned short*)(ws + 17301504);  // 37,748,736 B
  unsigned short* vTp   = (unsigned short*)(ws + 55050240);  // 12,582,912 B
  unsigned short* aoutb = (unsigned short*)(ws + 67633152);  // 12,582,912 B
  unsigned short* pbf   = (unsigned short*)(ws + 80216064);  //     16,384 B

  prep_kernel<<<4256, 256, 0, stream>>>(x, qkv_w, proj_w, policy, xb, wqkv, wproj, pbf);
  gemm_bt<0, 128, 4><<<dim3(18 * 64), 256, 0, stream>>>(xb, wqkv, qkvb, nullptr, 8192, 2304, 768);
  transpose_v<<<dim3(16, 96), 256, 0, stream>>>(qkvb, policy, vTp);
  attn_kernel<<<dim3(768), 256, 0, stream>>>(qkvb, vTp, pbf, policy, aoutb);
  gemm_bt<1, 64, 3><<<dim3(12 * 64), 256, 0, stream>>>(aoutb, wproj, out, proj_b, 8192, 768, 768);
}

// Round 15
// 180.299 us; speedup vs baseline: 1.0061x; 1.0061x over previous
//
#include <hip/hip_runtime.h>

typedef __bf16 bf16x8 __attribute__((ext_vector_type(8)));
typedef float floatx4 __attribute__((ext_vector_type(4)));

#define EPSF 1e-6f

__device__ inline unsigned short f2bf(float f) {  // RNE
  union { float f; unsigned u; } x; x.f = f;
  unsigned r = x.u + 0x7FFFu + ((x.u >> 16) & 1u);
  return (unsigned short)(r >> 16);
}
__device__ inline float bf2f(unsigned short u) {
  union { unsigned u; float f; } x; x.u = ((unsigned)u) << 16;
  return x.f;
}
// pack two f32 -> bf16x2 dword, round-half-up
__device__ inline unsigned pk2bf(float lo, float hi) {
  union { float f; unsigned u; } a, b; a.f = lo; b.f = hi;
  unsigned ua = a.u + 0x8000u, ub = b.u + 0x8000u;
  return (ub & 0xFFFF0000u) | (ua >> 16);
}
// single-instruction v_exp_f32 (input in log2 domain — scale folded into Q weights)
__device__ inline float fexp2(float x) { return __builtin_amdgcn_exp2f(x); }

__device__ inline floatx4 mfma16(bf16x8 a, bf16x8 b, floatx4 c) {
  return __builtin_amdgcn_mfma_f32_16x16x32_bf16(a, b, c, 0, 0, 0);
}

__device__ inline void gll16(const unsigned short* g, unsigned short* l) {
  __builtin_amdgcn_global_load_lds((__attribute__((address_space(1))) void*)g,
                                   (__attribute__((address_space(3))) void*)l, 16, 0, 0);
}

// ctx permutation sigma^-1 (PV k-dim): stored pos p in a 32-chunk holds original ctx c
__device__ __host__ inline int sigma_inv(int p) {
  const int qq = p >> 3, jj = p & 7;
  return (jj < 4) ? (qq * 4 + jj) : (16 + qq * 4 + jj - 4);
}

// ---------- merged prep: x cast | qkv_w cast (Q-scaled) | proj_w cast with k-dim gather-perm | policy pack ----------
// feature perm pi(c) = 4*(c%16) + c/16 within each 64-block (qkv GEMM packed epilogue)
__global__ __launch_bounds__(256) void prep_kernel(const float* __restrict__ x,
                                                   const float* __restrict__ qkv_w,
                                                   const float* __restrict__ proj_w,
                                                   const float* __restrict__ policy,
                                                   unsigned short* __restrict__ xb,
                                                   unsigned short* __restrict__ wqkv,
                                                   unsigned short* __restrict__ wproj,
                                                   unsigned short* __restrict__ pbf) {
  const int bid = blockIdx.x, tid = threadIdx.x;
  if (bid < 3072) {  // x cast: 6291456 elems
    const int i = bid * 2048 + tid * 8;
    float4 v0 = *(const float4*)(x + i);
    float4 v1 = *(const float4*)(x + i + 4);
    __align__(16) unsigned short o[8] = {f2bf(v0.x), f2bf(v0.y), f2bf(v0.z), f2bf(v0.w),
                                         f2bf(v1.x), f2bf(v1.y), f2bf(v1.z), f2bf(v1.w)};
    *(float4*)(xb + i) = *(float4*)o;
  } else if (bid < 3936) {  // qkv_w cast: 1769472 elems, first 589824 (Q rows) * 0.125*log2(e)
    const int i = (bid - 3072) * 2048 + tid * 8;
    const float s = (i < 589824) ? 0.18033688011112042f : 1.0f;
    float4 v0 = *(const float4*)(qkv_w + i);
    float4 v1 = *(const float4*)(qkv_w + i + 4);
    __align__(16) unsigned short o[8] = {
        f2bf(v0.x * s), f2bf(v0.y * s), f2bf(v0.z * s), f2bf(v0.w * s),
        f2bf(v1.x * s), f2bf(v1.y * s), f2bf(v1.z * s), f2bf(v1.w * s)};
    *(float4*)(wqkv + i) = *(float4*)o;
  } else if (bid < 4224) {  // proj_w cast with in-dim pi perm: 589824 elems
    const int i0 = (bid - 3936) * 2048 + tid * 8;  // dest index (row-contig)
    const int base = (i0 / 768) * 768 + ((i0 % 768) & ~63);
    __align__(16) unsigned short o[8];
#pragma unroll
    for (int t = 0; t < 8; t++) {
      const int cp = (i0 + t) & 63;                 // stored position within 64-block
      const int c = 16 * (cp & 3) + (cp >> 2);      // original column
      o[t] = f2bf(proj_w[base + c]);
    }
    *(float4*)(wproj + i0) = *(float4*)o;
  } else {  // policy pack: 8192 elems, ctx-perm sigma per 32-chunk
    const int idx = (bid - 4224) * 256 + tid;
    const int b = idx >> 10, g = idx & 1023;
    const int c = ((g >> 5) << 5) + sigma_inv(g & 31);
    pbf[idx] = f2bf(policy[b * 1024 + c]);
  }
}

// ---------- bf16 GEMM: BK=64, XOR-8 swizzle, XCD y-band grid swizzle for L2 locality ----------
// 1D grid; y = (bid&7)*8 + ((bid>>3)&7), x = bid>>6 — XCD k touches one 1024-row A band.
// EP=0 (BN=128): bf16 out with 64-block col-perm pi (packed dwordx2 stores).
// EP=1 (BN=64): f32 out + bias, natural layout.  W = min waves/EU.
template <int EP, int BN, int W>
__global__ __launch_bounds__(256, W) void gemm_bt(const unsigned short* __restrict__ A,
                                                  const unsigned short* __restrict__ Bt,
                                                  void* __restrict__ Cout,
                                                  const float* __restrict__ bias,
                                                  int M, int N, int K) {
  constexpr int J = BN / 32;
  __shared__ __align__(16) unsigned short sA[128 * 64];
  __shared__ __align__(16) unsigned short sB[BN * 64];
  const int bid = blockIdx.x;
  const int yb = (bid & 7) * 8 + ((bid >> 3) & 7);
  const int xb_ = bid >> 6;
  const int m0 = yb * 128, n0 = xb_ * BN;
  const int tid = threadIdx.x;
  const int lane = tid & 63, wave = tid >> 6;
  const int qd = lane >> 4, l15 = lane & 15;
  const int wr = (wave >> 1) * 64, wc = (wave & 1) * (BN / 2);
  const int srow = tid >> 3;
  const int scb = (tid & 7) ^ (srow & 7);
  const unsigned short* Ag = A + (long)(m0 + srow) * K + scb * 8;
  const unsigned short* Bg = Bt + (long)(n0 + srow) * K + scb * 8;
  const int x7 = l15 & 7;
  floatx4 acc[4][J] = {};
  for (int k0 = 0; k0 < K; k0 += 64) {
    __syncthreads();
#pragma unroll
    for (int p = 0; p < 4; p++) gll16(Ag + (long)(p * 32) * K + k0, sA + p * 2048 + wave * 512);
#pragma unroll
    for (int p = 0; p < J; p++) gll16(Bg + (long)(p * 32) * K + k0, sB + p * 2048 + wave * 512);
    __syncthreads();
#pragma unroll
    for (int s = 0; s < 2; s++) {
      const int cw = ((s * 4 + qd) ^ x7) * 8;
      bf16x8 af[4], bf[J];
#pragma unroll
      for (int i = 0; i < 4; i++) af[i] = *(const bf16x8*)&sA[(wr + i * 16 + l15) * 64 + cw];
#pragma unroll
      for (int j = 0; j < J; j++) bf[j] = *(const bf16x8*)&sB[(wc + j * 16 + l15) * 64 + cw];
#pragma unroll
      for (int i = 0; i < 4; i++)
#pragma unroll
        for (int j = 0; j < J; j++) acc[i][j] = mfma16(af[i], bf[j], acc[i][j]);
    }
  }
  if constexpr (EP == 0) {
    // feature f = wc + 16j + l15 stored at col' = wc + 4*l15 + j  (pi within 64-block)
#pragma unroll
    for (int i = 0; i < 4; i++)
#pragma unroll
      for (int r = 0; r < 4; r++) {
        const int row = m0 + wr + i * 16 + qd * 4 + r;
        __align__(8) unsigned short pk[4];
#pragma unroll
        for (int j = 0; j < 4; j++) pk[j] = f2bf(acc[i][j][r]);
        *(uint2*)((unsigned short*)Cout + (long)row * N + n0 + wc + 4 * l15) = *(uint2*)pk;
      }
  } else {
#pragma unroll
    for (int i = 0; i < 4; i++)
#pragma unroll
      for (int j = 0; j < J; j++) {
        const int col = n0 + wc + j * 16 + l15;
#pragma unroll
        for (int r = 0; r < 4; r++) {
          const int row = m0 + wr + i * 16 + qd * 4 + r;
          ((float*)Cout)[(long)row * N + col] = acc[i][j][r] + bias[col];
        }
      }
  }
}

// ---------- V transpose + policy fold + ctx sigma-perm ----------
__global__ __launch_bounds__(256) void transpose_v(const unsigned short* __restrict__ qkv,
                                                   const float* __restrict__ policy,
                                                   unsigned short* __restrict__ vTp) {
  __shared__ unsigned short tile[64][72];
  __shared__ float sPol[64];
  const int bh = blockIdx.y;
  const int b = bh / 12, h = bh % 12;
  const int n0 = blockIdx.x * 64;
  const int t = threadIdx.x;
  if (t < 64) sPol[t] = policy[b * 1024 + n0 + t];
  {
    const int nr = t >> 2, dc = (t & 3) * 16;
    const unsigned short* src = qkv + (long)(b * 1024 + n0 + nr) * 2304 + 2 * 768 + h * 64 + dc;
    float4 v0 = *(const float4*)src;
    float4 v1 = *(const float4*)(src + 8);
    *(float4*)&tile[nr][dc] = v0;
    *(float4*)&tile[nr][dc + 8] = v1;
  }
  __syncthreads();
  {
    const int d = t >> 2, nc = (t & 3) * 16;
    __align__(16) unsigned short o[16];
#pragma unroll
    for (int jj = 0; jj < 16; jj++) {
      const int cc = nc + jj;
      const int cl = (cc & 32) + sigma_inv(cc & 31);
      o[jj] = f2bf(bf2f(tile[cl][d]) * sPol[cl]);
    }
    unsigned short* dst = vTp + (long)(bh * 64 + d) * 1024 + n0 + nc;
    *(float4*)dst = *(float4*)&o[0];
    *(float4*)(dst + 8) = *(float4*)&o[8];
  }
}

// ---------- attention v11: v8 loop body, 64 q-rows/block (16 q/wave) -> 1536 blocks = 6 blocks/CU ----------
// Occupancy was the binding constraint (768-block grid = 3/CU, 23% occ); chain is now short LDS work,
// so doubling independent barrier groups per CU hides it (unlike R4's pre-staging attempt).
__global__ __launch_bounds__(256, 6) void attn_kernel(const unsigned short* __restrict__ qkv,
                                                      const unsigned short* __restrict__ vTp,
                                                      const unsigned short* __restrict__ pbf,
                                                      const float* __restrict__ policy,
                                                      unsigned short* __restrict__ aout) {
  __shared__ __align__(16) unsigned short sK[2][2048];  // 32 ctx x 64 d, slot cb = c ^ (row&7)
  __shared__ __align__(16) unsigned short sV[2][2048];  // 64 d x 32 ctx, slot cb = c ^ ((d^(d>>2))&3)
  __shared__ __align__(16) unsigned short sPv[1024];
  __shared__ float sD[4][16];
  const int bid = blockIdx.x;
  const int bh = bid % 96, qt = bid / 96;  // bh-fast for XCD L2 locality; qt 0..15
  const int b = bh / 12, h = bh % 12;
  const int tid = threadIdx.x;
  const int wave = tid >> 6, lane = tid & 63;
  const int qd = lane >> 4, l15 = lane & 15;
  const int q0 = qt * 64 + wave * 16;
  const unsigned short* qb = qkv + (long)(b * 1024 + q0 + l15) * 2304 + h * 64 + qd * 8;
  bf16x8 qf0 = *(const bf16x8*)qb;  // Q pre-scaled by 0.125*log2e
  bf16x8 qf1 = *(const bf16x8*)(qb + 32);
  if (tid < 128) *(float4*)(sPv + tid * 8) = *(const float4*)(pbf + b * 1024 + tid * 8);
  const int krow = wave * 8 + (lane >> 3);
  const int kcb = (lane & 7) ^ (lane >> 3);
  const unsigned short* kgl = qkv + (long)(b * 1024 + krow) * 2304 + 768 + h * 64 + kcb * 8;
  const int vrow = tid >> 2;
  const int vcb = (tid & 3) ^ ((vrow ^ (vrow >> 2)) & 3);
  const unsigned short* vgl = vTp + (long)(bh * 64 + vrow) * 1024 + vcb * 8;
  const int x7 = l15 & 7;
  const int vsw = (qd ^ ((l15 ^ (l15 >> 2)) & 3)) * 8;
  floatx4 O[4] = {};
  floatx4 Dl = {};
  const floatx4 z = {0.f, 0.f, 0.f, 0.f};
  // prologue: stage chunk 0 into buf 0, publish to all waves
  gll16(kgl, &sK[0][wave * 512]);
  gll16(vgl, &sV[0][wave * 512]);
  __builtin_amdgcn_s_waitcnt(0);
  __syncthreads();
  for (int it = 0; it < 32; ++it) {
    const int buf = it & 1;
    if (it < 31) {  // prefetch chunk it+1 — in flight across this iteration's full compute
      gll16(kgl + (long)(32 * (it + 1)) * 2304, &sK[buf ^ 1][wave * 512]);
      gll16(vgl + 32 * (it + 1), &sV[buf ^ 1][wave * 512]);
    }
    bf16x8 k00 = *(const bf16x8*)&sK[buf][(0 * 16 + l15) * 64 + ((0 + qd) ^ x7) * 8];
    bf16x8 k01 = *(const bf16x8*)&sK[buf][(0 * 16 + l15) * 64 + ((4 + qd) ^ x7) * 8];
    bf16x8 k10 = *(const bf16x8*)&sK[buf][(1 * 16 + l15) * 64 + ((0 + qd) ^ x7) * 8];
    bf16x8 k11 = *(const bf16x8*)&sK[buf][(1 * 16 + l15) * 64 + ((4 + qd) ^ x7) * 8];
    bf16x8 pv = *(const bf16x8*)&sPv[it * 32 + qd * 8];
    // S^T = K·Q^T: lane (q=l15,qd) gets S[q][ctx = tile*16 + qd*4+r]
    floatx4 tA = mfma16(k01, qf1, mfma16(k00, qf0, z));  // ctx 0-15
    floatx4 tB = mfma16(k11, qf1, mfma16(k10, qf0, z));  // ctx 16-31
    // P A-fragment in-register: k-slot qd*8+j holds ctx sigma_inv
    uint4 pu;
    pu.x = pk2bf(fexp2(tA[0]), fexp2(tA[1]));
    pu.y = pk2bf(fexp2(tA[2]), fexp2(tA[3]));
    pu.z = pk2bf(fexp2(tB[0]), fexp2(tB[1]));
    pu.w = pk2bf(fexp2(tB[2]), fexp2(tB[3]));
    bf16x8 pf = *(bf16x8*)&pu;
    bf16x8 vf0 = *(const bf16x8*)&sV[buf][(0 * 16 + l15) * 32 + vsw];
    bf16x8 vf1 = *(const bf16x8*)&sV[buf][(1 * 16 + l15) * 32 + vsw];
    bf16x8 vf2 = *(const bf16x8*)&sV[buf][(2 * 16 + l15) * 32 + vsw];
    bf16x8 vf3 = *(const bf16x8*)&sV[buf][(3 * 16 + l15) * 32 + vsw];
    Dl = mfma16(pf, pv, Dl);
    O[0] = mfma16(pf, vf0, O[0]);
    O[1] = mfma16(pf, vf1, O[1]);
    O[2] = mfma16(pf, vf2, O[2]);
    O[3] = mfma16(pf, vf3, O[3]);
    __builtin_amdgcn_s_waitcnt(0);  // drain own prefetch DMA before barrier (cross-wave publish)
    __syncthreads();
  }
  // ---- diagonal correction: O[q] += e_qq(1-p_q) V[q]; l_q += e_qq(1-p_q) ----
  {
    const unsigned short* kd = qkv + (long)(b * 1024 + q0 + l15) * 2304 + 768 + h * 64 + qd * 8;
    bf16x8 kd0 = *(const bf16x8*)kd;
    bf16x8 kd1 = *(const bf16x8*)(kd + 32);
    float part = 0.f;
#pragma unroll
    for (int jj = 0; jj < 8; jj++)
      part += (float)qf0[jj] * (float)kd0[jj] + (float)qf1[jj] * (float)kd1[jj];
    part += __shfl_xor(part, 16);
    part += __shfl_xor(part, 32);
    if (qd == 0) {
      const float p0 = policy[b * 1024 + q0 + l15];
      sD[wave][l15] = fexp2(part) * (1.0f - p0);
    }
    __builtin_amdgcn_s_waitcnt(0);
    // vdiag read in PERMUTED d' space (stored positions) to match O's d' columns:
    // O col j*16+l15 = vTp row d' = j*16+l15; qkvb stores d' contiguously, so read stored pos directly
    const unsigned short* vdiag = qkv + (long)(b * 1024 + q0) * 2304 + 1536 + h * 64 + l15;
#pragma unroll
    for (int r = 0; r < 4; r++) {
      const int row = qd * 4 + r;
      const float cv = sD[wave][row];
#pragma unroll
      for (int j = 0; j < 4; j++)
        O[j][r] += cv * bf2f(vdiag[(long)row * 2304 + j * 16]);
      Dl[r] += cv;
    }
  }
  const long ob = (long)(b * 1024 + q0 + qd * 4) * 768 + h * 64 + l15;
#pragma unroll
  for (int r = 0; r < 4; r++) {
    const float li = 1.0f / (Dl[r] + EPSF);
#pragma unroll
    for (int j = 0; j < 4; j++)
      aout[ob + (long)r * 768 + j * 16] = f2bf(O[j][r] * li);
  }
}

extern "C" void kernel_launch(void* const* d_in, const int* in_sizes, int n_in,
                              void* d_out, int out_size, void* d_ws, size_t ws_size,
                              hipStream_t stream) {
  const float* x      = (const float*)d_in[0];   // [8,1024,768]
  const float* policy = (const float*)d_in[1];   // [8,1024,1]
  const float* qkv_w  = (const float*)d_in[2];   // [2304,768]
  const float* proj_w = (const float*)d_in[3];   // [768,768]
  const float* proj_b = (const float*)d_in[4];   // [768]
  float* out = (float*)d_out;                    // [8,1024,768] fp32

  char* ws = (char*)d_ws;
  unsigned short* xb    = (unsigned short*)(ws + 0);         // 12,582,912 B
  unsigned short* wqkv  = (unsigned short*)(ws + 12582912);  //  3,538,944 B
  unsigned short* wproj = (unsigned short*)(ws + 16121856);  //  1,179,648 B
  unsigned short* qkvb  = (unsigned short*)(ws + 17301504);  // 37,748,736 B
  unsigned short* vTp   = (unsigned short*)(ws + 55050240);  // 12,582,912 B
  unsigned short* aoutb = (unsigned short*)(ws + 67633152);  // 12,582,912 B
  unsigned short* pbf   = (unsigned short*)(ws + 80216064);  //     16,384 B

  prep_kernel<<<4256, 256, 0, stream>>>(x, qkv_w, proj_w, policy, xb, wqkv, wproj, pbf);
  gemm_bt<0, 128, 4><<<dim3(18 * 64), 256, 0, stream>>>(xb, wqkv, qkvb, nullptr, 8192, 2304, 768);
  transpose_v<<<dim3(16, 96), 256, 0, stream>>>(qkvb, policy, vTp);
  attn_kernel<<<dim3(1536), 256, 0, stream>>>(qkvb, vTp, pbf, policy, aoutb);
  gemm_bt<1, 64, 3><<<dim3(12 * 64), 256, 0, stream>>>(aoutb, wproj, out, proj_b, 8192, 768, 768);
}

// Round 16
// 174.135 us; speedup vs baseline: 1.0417x; 1.0354x over previous
//
#include <hip/hip_runtime.h>

typedef __bf16 bf16x8 __attribute__((ext_vector_type(8)));
typedef float floatx4 __attribute__((ext_vector_type(4)));

#define EPSF 1e-6f

__device__ inline unsigned short f2bf(float f) {  // RNE
  union { float f; unsigned u; } x; x.f = f;
  unsigned r = x.u + 0x7FFFu + ((x.u >> 16) & 1u);
  return (unsigned short)(r >> 16);
}
__device__ inline float bf2f(unsigned short u) {
  union { unsigned u; float f; } x; x.u = ((unsigned)u) << 16;
  return x.f;
}
// pack two f32 -> bf16x2 dword, round-half-up
__device__ inline unsigned pk2bf(float lo, float hi) {
  union { float f; unsigned u; } a, b; a.f = lo; b.f = hi;
  unsigned ua = a.u + 0x8000u, ub = b.u + 0x8000u;
  return (ub & 0xFFFF0000u) | (ua >> 16);
}
// single-instruction v_exp_f32 (input in log2 domain — scale folded into Q weights)
__device__ inline float fexp2(float x) { return __builtin_amdgcn_exp2f(x); }

__device__ inline floatx4 mfma16(bf16x8 a, bf16x8 b, floatx4 c) {
  return __builtin_amdgcn_mfma_f32_16x16x32_bf16(a, b, c, 0, 0, 0);
}

__device__ inline void gll16(const unsigned short* g, unsigned short* l) {
  __builtin_amdgcn_global_load_lds((__attribute__((address_space(1))) void*)g,
                                   (__attribute__((address_space(3))) void*)l, 16, 0, 0);
}

// ctx permutation sigma^-1 (PV k-dim): stored pos p in a 32-chunk holds original ctx c
__device__ __host__ inline int sigma_inv(int p) {
  const int qq = p >> 3, jj = p & 7;
  return (jj < 4) ? (qq * 4 + jj) : (16 + qq * 4 + jj - 4);
}

// ---------- merged prep: x cast | qkv_w cast (Q-scaled) | proj_w cast with k-dim gather-perm | policy pack ----------
// feature perm pi(c) = 4*(c%16) + c/16 within each 64-block (qkv GEMM packed epilogue)
__global__ __launch_bounds__(256) void prep_kernel(const float* __restrict__ x,
                                                   const float* __restrict__ qkv_w,
                                                   const float* __restrict__ proj_w,
                                                   const float* __restrict__ policy,
                                                   unsigned short* __restrict__ xb,
                                                   unsigned short* __restrict__ wqkv,
                                                   unsigned short* __restrict__ wproj,
                                                   unsigned short* __restrict__ pbf) {
  const int bid = blockIdx.x, tid = threadIdx.x;
  if (bid < 3072) {  // x cast: 6291456 elems
    const int i = bid * 2048 + tid * 8;
    float4 v0 = *(const float4*)(x + i);
    float4 v1 = *(const float4*)(x + i + 4);
    __align__(16) unsigned short o[8] = {f2bf(v0.x), f2bf(v0.y), f2bf(v0.z), f2bf(v0.w),
                                         f2bf(v1.x), f2bf(v1.y), f2bf(v1.z), f2bf(v1.w)};
    *(float4*)(xb + i) = *(float4*)o;
  } else if (bid < 3936) {  // qkv_w cast: 1769472 elems, first 589824 (Q rows) * 0.125*log2(e)
    const int i = (bid - 3072) * 2048 + tid * 8;
    const float s = (i < 589824) ? 0.18033688011112042f : 1.0f;
    float4 v0 = *(const float4*)(qkv_w + i);
    float4 v1 = *(const float4*)(qkv_w + i + 4);
    __align__(16) unsigned short o[8] = {
        f2bf(v0.x * s), f2bf(v0.y * s), f2bf(v0.z * s), f2bf(v0.w * s),
        f2bf(v1.x * s), f2bf(v1.y * s), f2bf(v1.z * s), f2bf(v1.w * s)};
    *(float4*)(wqkv + i) = *(float4*)o;
  } else if (bid < 4224) {  // proj_w cast with in-dim pi perm: 589824 elems
    const int i0 = (bid - 3936) * 2048 + tid * 8;  // dest index (row-contig)
    const int base = (i0 / 768) * 768 + ((i0 % 768) & ~63);
    __align__(16) unsigned short o[8];
#pragma unroll
    for (int t = 0; t < 8; t++) {
      const int cp = (i0 + t) & 63;                 // stored position within 64-block
      const int c = 16 * (cp & 3) + (cp >> 2);      // original column
      o[t] = f2bf(proj_w[base + c]);
    }
    *(float4*)(wproj + i0) = *(float4*)o;
  } else {  // policy pack: 8192 elems, ctx-perm sigma per 32-chunk
    const int idx = (bid - 4224) * 256 + tid;
    const int b = idx >> 10, g = idx & 1023;
    const int c = ((g >> 5) << 5) + sigma_inv(g & 31);
    pbf[idx] = f2bf(policy[b * 1024 + c]);
  }
}

// ---------- bf16 GEMM: BK=64, XOR-8 swizzle, XCD y-band grid swizzle for L2 locality ----------
// 1D grid; y = (bid&7)*8 + ((bid>>3)&7), x = bid>>6 — XCD k touches one 1024-row A band.
// EP=0 (BN=128): bf16 out with 64-block col-perm pi (packed dwordx2 stores).
// EP=1 (BN=64): f32 out + bias, natural layout.  W = min waves/EU.
template <int EP, int BN, int W>
__global__ __launch_bounds__(256, W) void gemm_bt(const unsigned short* __restrict__ A,
                                                  const unsigned short* __restrict__ Bt,
                                                  void* __restrict__ Cout,
                                                  const float* __restrict__ bias,
                                                  int M, int N, int K) {
  constexpr int J = BN / 32;
  __shared__ __align__(16) unsigned short sA[128 * 64];
  __shared__ __align__(16) unsigned short sB[BN * 64];
  const int bid = blockIdx.x;
  const int yb = (bid & 7) * 8 + ((bid >> 3) & 7);
  const int xb_ = bid >> 6;
  const int m0 = yb * 128, n0 = xb_ * BN;
  const int tid = threadIdx.x;
  const int lane = tid & 63, wave = tid >> 6;
  const int qd = lane >> 4, l15 = lane & 15;
  const int wr = (wave >> 1) * 64, wc = (wave & 1) * (BN / 2);
  const int srow = tid >> 3;
  const int scb = (tid & 7) ^ (srow & 7);
  const unsigned short* Ag = A + (long)(m0 + srow) * K + scb * 8;
  const unsigned short* Bg = Bt + (long)(n0 + srow) * K + scb * 8;
  const int x7 = l15 & 7;
  floatx4 acc[4][J] = {};
  for (int k0 = 0; k0 < K; k0 += 64) {
    __syncthreads();
#pragma unroll
    for (int p = 0; p < 4; p++) gll16(Ag + (long)(p * 32) * K + k0, sA + p * 2048 + wave * 512);
#pragma unroll
    for (int p = 0; p < J; p++) gll16(Bg + (long)(p * 32) * K + k0, sB + p * 2048 + wave * 512);
    __syncthreads();
#pragma unroll
    for (int s = 0; s < 2; s++) {
      const int cw = ((s * 4 + qd) ^ x7) * 8;
      bf16x8 af[4], bf[J];
#pragma unroll
      for (int i = 0; i < 4; i++) af[i] = *(const bf16x8*)&sA[(wr + i * 16 + l15) * 64 + cw];
#pragma unroll
      for (int j = 0; j < J; j++) bf[j] = *(const bf16x8*)&sB[(wc + j * 16 + l15) * 64 + cw];
#pragma unroll
      for (int i = 0; i < 4; i++)
#pragma unroll
        for (int j = 0; j < J; j++) acc[i][j] = mfma16(af[i], bf[j], acc[i][j]);
    }
  }
  if constexpr (EP == 0) {
    // feature f = wc + 16j + l15 stored at col' = wc + 4*l15 + j  (pi within 64-block)
#pragma unroll
    for (int i = 0; i < 4; i++)
#pragma unroll
      for (int r = 0; r < 4; r++) {
        const int row = m0 + wr + i * 16 + qd * 4 + r;
        __align__(8) unsigned short pk[4];
#pragma unroll
        for (int j = 0; j < 4; j++) pk[j] = f2bf(acc[i][j][r]);
        *(uint2*)((unsigned short*)Cout + (long)row * N + n0 + wc + 4 * l15) = *(uint2*)pk;
      }
  } else {
#pragma unroll
    for (int i = 0; i < 4; i++)
#pragma unroll
      for (int j = 0; j < J; j++) {
        const int col = n0 + wc + j * 16 + l15;
#pragma unroll
        for (int r = 0; r < 4; r++) {
          const int row = m0 + wr + i * 16 + qd * 4 + r;
          ((float*)Cout)[(long)row * N + col] = acc[i][j][r] + bias[col];
        }
      }
  }
}

// ---------- V transpose + policy fold + ctx sigma-perm ----------
__global__ __launch_bounds__(256) void transpose_v(const unsigned short* __restrict__ qkv,
                                                   const float* __restrict__ policy,
                                                   unsigned short* __restrict__ vTp) {
  __shared__ unsigned short tile[64][72];
  __shared__ float sPol[64];
  const int bh = blockIdx.y;
  const int b = bh / 12, h = bh % 12;
  const int n0 = blockIdx.x * 64;
  const int t = threadIdx.x;
  if (t < 64) sPol[t] = policy[b * 1024 + n0 + t];
  {
    const int nr = t >> 2, dc = (t & 3) * 16;
    const unsigned short* src = qkv + (long)(b * 1024 + n0 + nr) * 2304 + 2 * 768 + h * 64 + dc;
    float4 v0 = *(const float4*)src;
    float4 v1 = *(const float4*)(src + 8);
    *(float4*)&tile[nr][dc] = v0;
    *(float4*)&tile[nr][dc + 8] = v1;
  }
  __syncthreads();
  {
    const int d = t >> 2, nc = (t & 3) * 16;
    __align__(16) unsigned short o[16];
#pragma unroll
    for (int jj = 0; jj < 16; jj++) {
      const int cc = nc + jj;
      const int cl = (cc & 32) + sigma_inv(cc & 31);
      o[jj] = f2bf(bf2f(tile[cl][d]) * sPol[cl]);
    }
    unsigned short* dst = vTp + (long)(bh * 64 + d) * 1024 + n0 + nc;
    *(float4*)dst = *(float4*)&o[0];
    *(float4*)(dst + 8) = *(float4*)&o[8];
  }
}

// ---------- attention v8 (measured best: 41.7-42.4 us): CTX=32/iter, 32 q/wave, 768 blocks, W=3 ----------
// Local-optimum evidence: v9 CTX=64 -> 46us; v10 sw-pipeline -> 41.6us (tie); v11 6 blk/CU -> 45.6us.
__global__ __launch_bounds__(256, 3) void attn_kernel(const unsigned short* __restrict__ qkv,
                                                      const unsigned short* __restrict__ vTp,
                                                      const unsigned short* __restrict__ pbf,
                                                      const float* __restrict__ policy,
                                                      unsigned short* __restrict__ aout) {
  __shared__ __align__(16) unsigned short sK[2][2048];  // 32 ctx x 64 d, slot cb = c ^ (row&7)
  __shared__ __align__(16) unsigned short sV[2][2048];  // 64 d x 32 ctx, slot cb = c ^ ((d^(d>>2))&3)
  __shared__ __align__(16) unsigned short sPv[1024];
  __shared__ float sD[4][32];
  const int bid = blockIdx.x;
  const int bh = bid % 96, qt = bid / 96;  // bh-fast for XCD L2 locality
  const int b = bh / 12, h = bh % 12;
  const int tid = threadIdx.x;
  const int wave = tid >> 6, lane = tid & 63;
  const int qd = lane >> 4, l15 = lane & 15;
  const int q0 = qt * 128 + wave * 32;
  const unsigned short* qb = qkv + (long)(b * 1024 + q0 + l15) * 2304 + h * 64 + qd * 8;
  bf16x8 qf00 = *(const bf16x8*)qb;  // Q pre-scaled by 0.125*log2e
  bf16x8 qf01 = *(const bf16x8*)(qb + 32);
  bf16x8 qf10 = *(const bf16x8*)(qb + (long)16 * 2304);
  bf16x8 qf11 = *(const bf16x8*)(qb + (long)16 * 2304 + 32);
  if (tid < 128) *(float4*)(sPv + tid * 8) = *(const float4*)(pbf + b * 1024 + tid * 8);
  const int krow = wave * 8 + (lane >> 3);
  const int kcb = (lane & 7) ^ (lane >> 3);
  const unsigned short* kgl = qkv + (long)(b * 1024 + krow) * 2304 + 768 + h * 64 + kcb * 8;
  const int vrow = tid >> 2;
  const int vcb = (tid & 3) ^ ((vrow ^ (vrow >> 2)) & 3);
  const unsigned short* vgl = vTp + (long)(bh * 64 + vrow) * 1024 + vcb * 8;
  const int x7 = l15 & 7;
  const int vsw = (qd ^ ((l15 ^ (l15 >> 2)) & 3)) * 8;
  floatx4 O0[4] = {}, O1[4] = {};
  floatx4 Dl0 = {}, Dl1 = {};
  const floatx4 z = {0.f, 0.f, 0.f, 0.f};
  // prologue: stage chunk 0 into buf 0, publish to all waves
  gll16(kgl, &sK[0][wave * 512]);
  gll16(vgl, &sV[0][wave * 512]);
  __builtin_amdgcn_s_waitcnt(0);
  __syncthreads();
  for (int it = 0; it < 32; ++it) {
    const int buf = it & 1;
    if (it < 31) {  // prefetch chunk it+1 — in flight across this iteration's full compute
      gll16(kgl + (long)(32 * (it + 1)) * 2304, &sK[buf ^ 1][wave * 512]);
      gll16(vgl + 32 * (it + 1), &sV[buf ^ 1][wave * 512]);
    }
    const int c0 = it * 32;
    bf16x8 k00 = *(const bf16x8*)&sK[buf][(0 * 16 + l15) * 64 + ((0 + qd) ^ x7) * 8];
    bf16x8 k01 = *(const bf16x8*)&sK[buf][(0 * 16 + l15) * 64 + ((4 + qd) ^ x7) * 8];
    bf16x8 k10 = *(const bf16x8*)&sK[buf][(1 * 16 + l15) * 64 + ((0 + qd) ^ x7) * 8];
    bf16x8 k11 = *(const bf16x8*)&sK[buf][(1 * 16 + l15) * 64 + ((4 + qd) ^ x7) * 8];
    bf16x8 pv = *(const bf16x8*)&sPv[c0 + qd * 8];
    // S^T = K·Q^T: lane (q=l15,qd) gets S[q][ctx = tile*16 + qd*4+r]
    floatx4 tA0 = mfma16(k01, qf01, mfma16(k00, qf00, z));
    floatx4 tB0 = mfma16(k11, qf01, mfma16(k10, qf00, z));
    floatx4 tA1 = mfma16(k01, qf11, mfma16(k00, qf10, z));
    floatx4 tB1 = mfma16(k11, qf11, mfma16(k10, qf10, z));
    uint4 pu0, pu1;
    pu0.x = pk2bf(fexp2(tA0[0]), fexp2(tA0[1]));
    pu0.y = pk2bf(fexp2(tA0[2]), fexp2(tA0[3]));
    pu0.z = pk2bf(fexp2(tB0[0]), fexp2(tB0[1]));
    pu0.w = pk2bf(fexp2(tB0[2]), fexp2(tB0[3]));
    pu1.x = pk2bf(fexp2(tA1[0]), fexp2(tA1[1]));
    pu1.y = pk2bf(fexp2(tA1[2]), fexp2(tA1[3]));
    pu1.z = pk2bf(fexp2(tB1[0]), fexp2(tB1[1]));
    pu1.w = pk2bf(fexp2(tB1[2]), fexp2(tB1[3]));
    bf16x8 pf0 = *(bf16x8*)&pu0;
    bf16x8 pf1 = *(bf16x8*)&pu1;
    bf16x8 vf0 = *(const bf16x8*)&sV[buf][(0 * 16 + l15) * 32 + vsw];
    bf16x8 vf1 = *(const bf16x8*)&sV[buf][(1 * 16 + l15) * 32 + vsw];
    bf16x8 vf2 = *(const bf16x8*)&sV[buf][(2 * 16 + l15) * 32 + vsw];
    bf16x8 vf3 = *(const bf16x8*)&sV[buf][(3 * 16 + l15) * 32 + vsw];
    Dl0 = mfma16(pf0, pv, Dl0);
    Dl1 = mfma16(pf1, pv, Dl1);
    O0[0] = mfma16(pf0, vf0, O0[0]); O1[0] = mfma16(pf1, vf0, O1[0]);
    O0[1] = mfma16(pf0, vf1, O0[1]); O1[1] = mfma16(pf1, vf1, O1[1]);
    O0[2] = mfma16(pf0, vf2, O0[2]); O1[2] = mfma16(pf1, vf2, O1[2]);
    O0[3] = mfma16(pf0, vf3, O0[3]); O1[3] = mfma16(pf1, vf3, O1[3]);
    __builtin_amdgcn_s_waitcnt(0);  // drain own prefetch DMA before barrier (cross-wave publish)
    __syncthreads();
  }
  // ---- diagonal correction: O[q] += e_qq(1-p_q) V[q]; l_q += e_qq(1-p_q) ----
  {
    const unsigned short* kd = qkv + (long)(b * 1024 + q0 + l15) * 2304 + 768 + h * 64 + qd * 8;
    bf16x8 kd00 = *(const bf16x8*)kd;
    bf16x8 kd01 = *(const bf16x8*)(kd + 32);
    bf16x8 kd10 = *(const bf16x8*)(kd + (long)16 * 2304);
    bf16x8 kd11 = *(const bf16x8*)(kd + (long)16 * 2304 + 32);
    float part0 = 0.f, part1 = 0.f;
#pragma unroll
    for (int jj = 0; jj < 8; jj++) {
      part0 += (float)qf00[jj] * (float)kd00[jj] + (float)qf01[jj] * (float)kd01[jj];
      part1 += (float)qf10[jj] * (float)kd10[jj] + (float)qf11[jj] * (float)kd11[jj];
    }
    part0 += __shfl_xor(part0, 16); part0 += __shfl_xor(part0, 32);
    part1 += __shfl_xor(part1, 16); part1 += __shfl_xor(part1, 32);
    const float p0 = policy[b * 1024 + q0 + l15];
    const float p1 = policy[b * 1024 + q0 + 16 + l15];
    if (qd == 0) {
      sD[wave][l15] = fexp2(part0) * (1.0f - p0);
      sD[wave][16 + l15] = fexp2(part1) * (1.0f - p1);
    }
    __builtin_amdgcn_s_waitcnt(0);
    const unsigned short* vdiag = qkv + (long)(b * 1024 + q0) * 2304 + 1536 + h * 64 + l15;
#pragma unroll
    for (int r = 0; r < 4; r++) {
      const int row = qd * 4 + r;
      const float c0v = sD[wave][row], c1v = sD[wave][16 + row];
#pragma unroll
      for (int j = 0; j < 4; j++) {
        O0[j][r] += c0v * bf2f(vdiag[(long)row * 2304 + j * 16]);
        O1[j][r] += c1v * bf2f(vdiag[(long)(16 + row) * 2304 + j * 16]);
      }
      Dl0[r] += c0v;
      Dl1[r] += c1v;
    }
  }
  const long ob = (long)(b * 1024 + q0 + qd * 4) * 768 + h * 64 + l15;
#pragma unroll
  for (int r = 0; r < 4; r++) {
    const float li0 = 1.0f / (Dl0[r] + EPSF);
    const float li1 = 1.0f / (Dl1[r] + EPSF);
#pragma unroll
    for (int j = 0; j < 4; j++) {
      aout[ob + (long)r * 768 + j * 16] = f2bf(O0[j][r] * li0);
      aout[ob + (long)(16 * 768) + r * 768 + j * 16] = f2bf(O1[j][r] * li1);
    }
  }
}

extern "C" void kernel_launch(void* const* d_in, const int* in_sizes, int n_in,
                              void* d_out, int out_size, void* d_ws, size_t ws_size,
                              hipStream_t stream) {
  const float* x      = (const float*)d_in[0];   // [8,1024,768]
  const float* policy = (const float*)d_in[1];   // [8,1024,1]
  const float* qkv_w  = (const float*)d_in[2];   // [2304,768]
  const float* proj_w = (const float*)d_in[3];   // [768,768]
  const float* proj_b = (const float*)d_in[4];   // [768]
  float* out = (float*)d_out;                    // [8,1024,768] fp32

  char* ws = (char*)d_ws;
  unsigned short* xb    = (unsigned short*)(ws + 0);         // 12,582,912 B
  unsigned short* wqkv  = (unsigned short*)(ws + 12582912);  //  3,538,944 B
  unsigned short* wproj = (unsigned short*)(ws + 16121856);  //  1,179,648 B
  unsigned short* qkvb  = (unsigned short*)(ws + 17301504);  // 37,748,736 B
  unsigned short* vTp   = (unsigned short*)(ws + 55050240);  // 12,582,912 B
  unsigned short* aoutb = (unsigned short*)(ws + 67633152);  // 12,582,912 B
  unsigned short* pbf   = (unsigned short*)(ws + 80216064);  //     16,384 B

  prep_kernel<<<4256, 256, 0, stream>>>(x, qkv_w, proj_w, policy, xb, wqkv, wproj, pbf);
  gemm_bt<0, 128, 4><<<dim3(18 * 64), 256, 0, stream>>>(xb, wqkv, qkvb, nullptr, 8192, 2304, 768);
  transpose_v<<<dim3(16, 96), 256, 0, stream>>>(qkvb, policy, vTp);
  attn_kernel<<<dim3(768), 256, 0, stream>>>(qkvb, vTp, pbf, policy, aoutb);
  gemm_bt<1, 64, 3><<<dim3(12 * 64), 256, 0, stream>>>(aoutb, wproj, out, proj_b, 8192, 768, 768);
}